// Round 17
// baseline (23.921 us; speedup 1.0000x reference)
//
#include <hip/hip_runtime.h>
#include <math.h>

#define NR 50      // rho grid points per dim
#define NP 200     // phi grid points per dim
#define NM 400     // mirrored width (2*NP)
#define SCADDF 1e-12f
#define BW 4       // band of K in fp32 (c5,c6 < fp32 eps) = band of L
#define LST 6      // L row stride: band t=4..1 at slots 0..3, diag at 4, pad at 5
#define DG 4
#define LROWS (NR + BW)
#define NCHOL 12   // exact chol columns; col-11 deviation from steady ~7e-5
#define RS 52      // row stride (floats); 52%4==0 -> float4 rows
#define RS4 13     // row stride in float4
#define TBW 25     // b-tile width (cols per block)
#define BHALO (TBW + 4)   // 29 b-halo rows
#define NCD (20 + BHALO)  // 49 solve RHS
#define ETS 30     // ETf row stride

// ws layout (in doubles)
#define OFF_PART 240000
#define NTA2 13           // a-tiles of 16 rows
#define NTB3 16           // b-tiles of 25 cols
#define NBLK (NTA2*NTB3)  // 208 blocks <= 256 CUs: no co-residency straggler

// Penalty kernel. vs R16: retiled to 16x25 output tiles -> 208 blocks (~<=1
// per CU). Serial chains unchanged; per-lane parallel work +15%.
__global__ __launch_bounds__(256) void penalty_kernel(
        const float* __restrict__ params,
        const float* __restrict__ x_rho,
        const float* __restrict__ y_rho,
        const float* __restrict__ x_phi,
        const float* __restrict__ y_phi,
        double* __restrict__ ws) {
    __shared__ __align__(16) float Lb[LROWS * LST];
    __shared__ float iDf[NR];
    __shared__ __align__(16) float Pf [NR * RS];    // params, pads zeroed
    __shared__ __align__(16) float ATf[20 * RS];    // a-halo rows (clamped)
    __shared__ __align__(16) float BTf[BHALO * RS]; // b-halo rows (mirror+clamp)
    __shared__ __align__(16) float CDf[NCD * RS];   // solved c(0..19)/d(20..48)
    __shared__ __align__(16) float Ef [20 * RS];    // E[a][k] = c_a^T P
    __shared__ float ETf[20 * ETS];                 // eps halo tile (20a x 29b)
    __shared__ double wsum[4];

    const int tid  = threadIdx.x;
    const int lane = tid & 63;
    const int ba = blockIdx.x / NTB3, bbt = blockIdx.x % NTB3;
    const int a0 = ba*16, b0 = bbt*TBW;

    const float Lr = y_rho[NR-1] - y_rho[0];
    const float sigma = 0.8f * Lr / (float)(NR - 1);
    const float inv2s2 = 1.0f / (2.0f * sigma * sigma);
    const float g = (x_phi[NP-1] - x_phi[0]) / (float)(NP - 1);
    const float pi_d = (float)(M_PI / 1.1);

    if (tid < 64) {
        // ---- wave 0: register/shuffle banded Cholesky (Toeplitz) ----
        const int t = lane;
        if (t < BW * LST) Lb[t] = 0.0f;             // zero rows 0..3
        float ct = 0.0f;
        if (t <= BW) {
            float d = y_rho[t] - y_rho[0];          // Toeplitz coefficient c_t
            ct = expf(-d*d*inv2s2);
        }
        float h1=0,h2=0,h3=0,h4=0;                  // last-4-column history
        float lastinv = 1.0f;
        for (int j = 0; j < NCHOL; ++j) {
            float s = ct;
            s -= __shfl(h4, t+4, 64) * __shfl(h4, 4, 64);
            s -= __shfl(h3, t+3, 64) * __shfl(h3, 3, 64);
            s -= __shfl(h2, t+2, 64) * __shfl(h2, 2, 64);
            s -= __shfl(h1, t+1, 64) * __shfl(h1, 1, 64);
            float invd = rsqrtf(__shfl(s, 0, 64));  // lane 0 holds diag dot
            float nv = 0.0f;
            if (t <= BW && j + t < NR) {
                nv = s * invd;                      // t=0: dgdot*rsqrt = sqrt
                Lb[(j+t)*LST + DG - t] = nv;
            }
            if (t == 0) iDf[j] = invd;
            lastinv = invd;
            h4=h3; h3=h2; h2=h1; h1=nv;
        }
        // steady state: only cols NCHOL..NCHOL+3 are read by the solve
        float steady = h1;
        for (int j = NCHOL; j < NCHOL + 4; ++j) {
            if (t <= BW) Lb[(j+t)*LST + DG - t] = steady;
            if (t == 0)  iDf[j] = lastinv;
        }
        if (t == 0) iDf[NCHOL+4] = lastinv;
    } else {
        // ---- waves 1-3 (overlap chol): stage P (pads zeroed) + tables ----
        for (int idx = tid - 64; idx < NR*NR; idx += 192)
            Pf[(idx/NR)*RS + (idx%NR)] = params[idx];
        for (int e = tid - 64; e < NR; e += 192) {
            Pf[e*RS + 50] = 0.0f; Pf[e*RS + 51] = 0.0f;
        }
        for (int e = tid - 64; e < 20*NR; e += 192) {
            int r = e / NR, iy = e % NR;
            int aab = a0 - 2 + r; aab = aab < 0 ? 0 : (aab > NP-1 ? NP-1 : aab);
            float da = y_phi[aab] - y_rho[iy];
            ATf[r*RS + iy] = expf(-da*da*inv2s2);
        }
        for (int e = tid - 64; e < BHALO*NR; e += 192) {
            int r = e / NR, iy = e % NR;
            int mb = b0 - 2 + r;  mb = mb < 0 ? 0 : (mb > NM-1 ? NM-1 : mb);
            int bb = (mb < NP) ? mb : (NM-1 - mb);   // mirror to base col
            float db = x_phi[bb] - x_rho[iy];
            BTf[r*RS + iy] = expf(-db*db*inv2s2);
        }
    }
    __syncthreads();

    // ---- lanes 0..48: solve K v = rhs, sliding 4-reg window ----
    if (tid < NCD) {
        const float* rhs = (tid < 20) ? (ATf + tid*RS) : (BTf + (tid-20)*RS);
        float* cd = CDf + tid*RS;
        // steady-region coefficients in registers (rows/cols >= NCHOL)
        const float a1 = Lb[(NCHOL+1)*LST + DG - 1];
        const float a2 = Lb[(NCHOL+2)*LST + DG - 2];
        const float a3 = Lb[(NCHOL+3)*LST + DG - 3];
        const float a4 = Lb[(NCHOL+4)*LST + DG - 4];
        const float iDs = iDf[NCHOL];

        float w1=0,w2=0,w3=0,w4=0;
        #pragma unroll 2
        for (int i = 0; i < NCHOL+4; ++i) {         // fwd boundary: LDS coeffs
            const float* Lr_ = Lb + i*LST + DG;
            float pre = rhs[i] - (Lr_[-4]*w4 + Lr_[-3]*w3);
            pre -= Lr_[-2]*w2;
            float s = (pre - Lr_[-1]*w1) * iDf[i];
            cd[i] = s;
            w4=w3; w3=w2; w2=w1; w1=s;
        }
        #pragma unroll 2
        for (int i = NCHOL+4; i < NR; ++i) {        // fwd steady: registers
            float pre = rhs[i] - (a4*w4 + a3*w3);
            pre -= a2*w2;
            float s = (pre - a1*w1) * iDs;
            cd[i] = s;
            w4=w3; w3=w2; w2=w1; w1=s;
        }
        float v1=0,v2=0,v3=0,v4=0;
        #pragma unroll 2
        for (int i = NR-1; i >= NCHOL; --i) {       // bwd steady: registers
            float pre = cd[i] - (a4*v4 + a3*v3);
            pre -= a2*v2;
            float s = (pre - a1*v1) * iDs;
            cd[i] = s;
            v4=v3; v3=v2; v2=v1; v1=s;
        }
        #pragma unroll 2
        for (int i = NCHOL-1; i >= 0; --i) {        // bwd boundary: LDS coeffs
            float pre = cd[i] - (Lb[(i+4)*LST + DG-4]*v4 + Lb[(i+3)*LST + DG-3]*v3);
            pre -= Lb[(i+2)*LST + DG-2]*v2;
            float s = (pre - Lb[(i+1)*LST + DG-1]*v1) * iDf[i];
            cd[i] = s;
            v4=v3; v3=v2; v2=v1; v1=s;
        }
        cd[50] = 0.0f; cd[51] = 0.0f;               // zero pad for float4 dots
    }
    __syncthreads();

    // ---- Ef[a][k] = sum_i c_a[i]*P[i][k] : float4 micro-tile ----
    {
        const float4* Pf4 = reinterpret_cast<const float4*>(Pf);
        float4* Ef4 = reinterpret_cast<float4*>(Ef);
        for (int u = tid; u < 20*RS4; u += 256) {
            int a = u / RS4, k4 = u % RS4;
            float4 acc = make_float4(0.f, 0.f, 0.f, 0.f);
            #pragma unroll 10
            for (int i = 0; i < NR; ++i) {
                float c = CDf[a*RS + i];
                float4 p = Pf4[i*RS4 + k4];
                acc.x += c*p.x; acc.y += c*p.y; acc.z += c*p.z; acc.w += c*p.w;
            }
            Ef4[a*RS4 + k4] = acc;
        }
    }
    __syncthreads();

    // ---- eps halo tile: ETf[r][c] = act( Ef[r] . d_c ) via float4 dots ----
    {
        const float4* Ef4 = reinterpret_cast<const float4*>(Ef);
        const float4* CD4 = reinterpret_cast<const float4*>(CDf);
        for (int u = tid; u < 20*BHALO; u += 256) {
            int r = u / BHALO, c = u % BHALO;
            const float4* e4 = Ef4 + r*RS4;
            const float4* d4 = CD4 + (20+c)*RS4;
            float s = 0.0f;
            #pragma unroll
            for (int k4 = 0; k4 < RS4; ++k4) {
                float4 a = e4[k4], b = d4[k4];
                s += a.x*b.x + a.y*b.y + a.z*b.z + a.w*b.w;
            }
            ETf[r*ETS + c] = 0.5f * (tanhf(0.1f * s) + 1.0f);
        }
    }
    __syncthreads();

    // ---- stencil derivatives + curvature penalty (fp32, fp64 accum) ----
    auto EXf = [&](int r, int k) -> float {
        int aab = a0 - 2 + r;
        if (aab == 0)      return (ETf[(r+1)*ETS+k] - ETf[r*ETS+k])     / g + SCADDF;
        if (aab == NP-1)   return (ETf[r*ETS+k]     - ETf[(r-1)*ETS+k]) / g + SCADDF;
        return (ETf[(r+1)*ETS+k] - ETf[(r-1)*ETS+k]) / (2.0f*g) + SCADDF;
    };
    auto EYf = [&](int r, int k) -> float {
        int bab = b0 - 2 + k;
        if (bab == 0)      return (ETf[r*ETS+k+1] - ETf[r*ETS+k])   / g + SCADDF;
        if (bab == NM-1)   return (ETf[r*ETS+k]   - ETf[r*ETS+k-1]) / g + SCADDF;
        return (ETf[r*ETS+k+1] - ETf[r*ETS+k-1]) / (2.0f*g) + SCADDF;
    };

    double local = 0.0;
    for (int u = tid; u < 16*TBW; u += 256) {       // 400 outputs, fixed order
        const int aa = u / TBW, bb_ = u % TBW;
        const int a = a0 + aa, b = b0 + bb_;
        if (a < NP) {                               // b < NM always
            const int ar = aa + 2, kc = bb_ + 2;
            const float exv = EXf(ar, kc);
            const float eyv = EYf(ar, kc);
            float exx, exy, eyy;
            if (a == 0)         exx = (EXf(ar+1,kc) - EXf(ar,kc))   / g;
            else if (a == NP-1) exx = (EXf(ar,kc)   - EXf(ar-1,kc)) / g;
            else                exx = (EXf(ar+1,kc) - EXf(ar-1,kc)) / (2.0f*g);
            if (b == 0)         exy = (EXf(ar,kc+1) - EXf(ar,kc))   / g;
            else if (b == NM-1) exy = (EXf(ar,kc)   - EXf(ar,kc-1)) / g;
            else                exy = (EXf(ar,kc+1) - EXf(ar,kc-1)) / (2.0f*g);
            if (b == 0)         eyy = (EYf(ar,kc+1) - EYf(ar,kc))   / g;
            else if (b == NM-1) eyy = (EYf(ar,kc)   - EYf(ar,kc-1)) / g;
            else                eyy = (EYf(ar,kc+1) - EYf(ar,kc-1)) / (2.0f*g);

            float epsv = sqrtf(exv*exv + eyv*eyv);
            const float epsv_min = 1.6666667e-33f;  // 1e-32/6
            if (epsv < epsv_min) epsv = epsv_min;
            const float kk = (exv*exv*eyy - 2.0f*exv*eyv*exy + eyv*eyv*exx)
                             / (epsv*epsv*epsv);
            const float cc = fabsf(kk * atanf(epsv / ETf[ar*ETS+kc])) - pi_d;
            float v = fmaxf(cc, 0.0f) * g * g;
            if (!isnan(v)) local += (double)v;
        }
    }

    // ---- per-wave shfl reduce (fixed tree) + single barrier ----
    #pragma unroll
    for (int off = 32; off > 0; off >>= 1)
        local += __shfl_down(local, off, 64);
    if (lane == 0) wsum[tid >> 6] = local;
    __syncthreads();
    if (tid == 0)
        (ws + OFF_PART)[blockIdx.x] = (wsum[0] + wsum[1]) + (wsum[2] + wsum[3]);
}

// ---------------- finalize: 1 wave, shfl-only deterministic sum -------------
__global__ __launch_bounds__(64) void finalize_kernel(
        const double* __restrict__ ws, float* __restrict__ out) {
    const double* part = ws + OFF_PART;
    const int t = threadIdx.x;                       // 64 threads
    double s = 0.0;
    for (int i = t; i < NBLK; i += 64) s += part[i]; // fixed order
    #pragma unroll
    for (int off = 32; off > 0; off >>= 1)
        s += __shfl_down(s, off, 64);
    if (t == 0) out[0] = (float)s;
}

extern "C" void kernel_launch(void* const* d_in, const int* in_sizes, int n_in,
                              void* d_out, int out_size, void* d_ws, size_t ws_size,
                              hipStream_t stream) {
    const float* params = (const float*)d_in[0];
    const float* x_rho  = (const float*)d_in[1];
    const float* y_rho  = (const float*)d_in[2];
    const float* x_phi  = (const float*)d_in[3];
    const float* y_phi  = (const float*)d_in[4];
    double* ws = (double*)d_ws;
    float* out = (float*)d_out;

    penalty_kernel<<<NBLK, 256, 0, stream>>>(
        params, x_rho, y_rho, x_phi, y_phi, ws);
    finalize_kernel<<<1, 64, 0, stream>>>(ws, out);
}